// Round 15
// baseline (387.173 us; speedup 1.0000x reference)
//
#include <hip/hip_runtime.h>
#include <hip/hip_bf16.h>
#include <math.h>

typedef __hip_bfloat16 bf16;
typedef __attribute__((ext_vector_type(8))) short short8;
typedef __attribute__((ext_vector_type(4))) float f32x4;

#define NNODES 2000
#define NEDGE_IN 16000
#define NEDGE 18000
#define NGRAPH 40
#define GATES_KS 80

__device__ __forceinline__ float bf2f(bf16 v){ return __bfloat162float(v); }
__device__ __forceinline__ bf16 f2bf(float v){ return __float2bfloat16(v); }
__device__ __forceinline__ short bfbits(float v){ bf16 t = __float2bfloat16(v); return *reinterpret_cast<short*>(&t); }
__device__ __forceinline__ float blo(unsigned u){ return __uint_as_float(u<<16); }
__device__ __forceinline__ float bhi(unsigned u){ return __uint_as_float(u & 0xffff0000u); }

// ---------- fused setup: mean_ea | prep_whh | wcvt | zero | gemm0 (layout-B output) ----------
__global__ __launch_bounds__(256) void k_setup(const float* __restrict__ ea, float* __restrict__ mean_ea,
                        const float* __restrict__ whh, unsigned* __restrict__ whhT2,
                        const float* __restrict__ w1a, const float* __restrict__ w1b,
                        const float* __restrict__ w2a, const float* __restrict__ w2b,
                        bf16* __restrict__ b1a, bf16* __restrict__ b1b,
                        bf16* __restrict__ b2a, bf16* __restrict__ b2b,
                        int* __restrict__ cnt, int* __restrict__ cursor,
                        const float* __restrict__ X, const float* __restrict__ Wa,
                        const float* __restrict__ Wb,
                        bf16* __restrict__ Ya, bf16* __restrict__ Yb){
  __shared__ float smem[2048];
  int bb = blockIdx.x, tid = threadIdx.x;
  if (bb >= 689){
    // ---- layer-0 GEMM (K=8), fused Wl+Wr; output row permuted to [n][g] ----
    int blk = bb - 689;
    for (int i = tid; i < 1024; i += 256){ smem[i] = Wa[i]; smem[1024+i] = Wb[i]; }
    __syncthreads();
    int j  = tid & 127;
    int rg = tid >> 7;
    size_t m0 = (size_t)blk*8 + (size_t)rg*4;      // m = g*2000 + n (4 rows, same g)
    int g = (int)(m0/NNODES), n = (int)(m0%NNODES);
    const float* x0 = X + m0*8;
    float a0=0.f,a1=0.f,a2=0.f,a3=0.f, b0=0.f,b1=0.f,b2=0.f,b3=0.f;
    #pragma unroll
    for (int k=0;k<8;k++){
      float wa = smem[k*128 + j], wb = smem[1024 + k*128 + j];
      float x_0 = x0[k], x_1 = x0[8+k], x_2 = x0[16+k], x_3 = x0[24+k];
      a0 += x_0*wa; a1 += x_1*wa; a2 += x_2*wa; a3 += x_3*wa;
      b0 += x_0*wb; b1 += x_1*wb; b2 += x_2*wb; b3 += x_3*wb;
    }
    const size_t RS = (size_t)NGRAPH*128;
    bf16* ya = Ya + ((size_t)n*NGRAPH + g)*128 + j;
    bf16* yb = Yb + ((size_t)n*NGRAPH + g)*128 + j;
    ya[0]=f2bf(a0); ya[RS]=f2bf(a1); ya[2*RS]=f2bf(a2); ya[3*RS]=f2bf(a3);
    yb[0]=f2bf(b0); yb[RS]=f2bf(b1); yb[2*RS]=f2bf(b2); yb[3*RS]=f2bf(b3);
  } else if (bb == 0){
    float* s0l = smem; float* s1l = smem + 256;
    float s0=0.f, s1=0.f;
    for (int e = tid; e < NEDGE_IN; e += 256){ s0 += ea[2*e]; s1 += ea[2*e+1]; }
    s0l[tid]=s0; s1l[tid]=s1; __syncthreads();
    for (int d=128; d>=1; d>>=1){
      if (tid < d){ s0l[tid]+=s0l[tid+d]; s1l[tid]+=s1l[tid+d]; }
      __syncthreads();
    }
    if (tid==0){ mean_ea[0]=s0l[0]/(float)NEDGE_IN; mean_ea[1]=s1l[0]/(float)NEDGE_IN; }
  } else if (bb < 513){
    int idx = (bb-1)*256 + tid;
    int j = idx >> 7, kp = idx & 127;
    unsigned ulo = (unsigned)(unsigned short)bfbits(whh[j*256 + 2*kp]);
    unsigned uhi = (unsigned)(unsigned short)bfbits(whh[j*256 + 2*kp + 1]);
    whhT2[kp*1024 + j] = (uhi<<16) | ulo;
  } else if (bb < 673){
    int idx = (bb-513)*256 + tid;
    const float* src; bf16* dst; int n, local;
    if (idx < 16384){ src=w1a; dst=b1a; n=128; local=idx; }
    else if (idx < 32768){ src=w1b; dst=b1b; n=128; local=idx-16384; }
    else if (idx < 36864){ src=w2a; dst=b2a; n=32; local=idx-32768; }
    else { src=w2b; dst=b2b; n=32; local=idx-36864; }
    int k = local / n, c = local % n;
    dst[c*128 + k] = f2bf(src[local]);
  } else {
    int idx = (bb-673)*256 + tid;
    if (idx < 2000) cnt[idx] = 0;
    else if (idx < 4000) cursor[idx-2000] = 0;
  }
}

__global__ void k_count(const int* __restrict__ ei, int* __restrict__ cnt){
  int e = blockIdx.x*256 + threadIdx.x;
  if (e >= NEDGE) return;
  int d = (e < NEDGE_IN) ? ei[NEDGE_IN + e] : (e - NEDGE_IN);
  atomicAdd(&cnt[d], 1);
}

__global__ void k_scan(const int* __restrict__ cnt, int* __restrict__ off){
  __shared__ int s[2048];
  int lane = threadIdx.x; // 64 threads
  for (int i = lane; i < 2048; i += 64) s[i] = (i < NNODES) ? cnt[i] : 0;
  __syncthreads();
  int base = lane*32, run = 0;
  for (int j=0;j<32;j++){ int t = s[base+j]; s[base+j] = run; run += t; }
  int x = run;
  for (int d=1; d<64; d<<=1){ int y = __shfl_up(x, d); if (lane >= d) x += y; }
  int chunkOff = x - run;
  for (int j=0;j<32;j++){ int idx = base+j; if (idx <= NNODES) off[idx] = chunkOff + s[idx]; }
}

__global__ void k_scatter(const int* __restrict__ ei, const int* __restrict__ off,
                          int* __restrict__ cursor, const float* __restrict__ ea,
                          const float* __restrict__ mean_ea,
                          int* __restrict__ csr_src, float2* __restrict__ eaP){
  int e = blockIdx.x*256 + threadIdx.x;
  if (e >= NEDGE) return;
  int d, sn; float2 a;
  if (e < NEDGE_IN){ sn = ei[e]; d = ei[NEDGE_IN+e]; a = ((const float2*)ea)[e]; }
  else { sn = e-NEDGE_IN; d = sn; a.x = mean_ea[0]; a.y = mean_ea[1]; }
  int p = off[d] + atomicAdd(&cursor[d], 1);
  csr_src[p] = sn;
  eaP[p] = a;
}

// ---------- MFMA GEMM, fused two B matrices (row-order agnostic) ----------
template<int N>
__global__ __launch_bounds__(256) void k_gemm_mf2(const bf16* __restrict__ A, const bf16* __restrict__ BTa,
                                                  const bf16* __restrict__ BTb,
                                                  bf16* __restrict__ Ya, bf16* __restrict__ Yb){
  const int NT = N/16;
  int lane = threadIdx.x & 63, wv = threadIdx.x >> 6;
  size_t m0 = (size_t)blockIdx.x*128 + (size_t)wv*32;
  int r = lane & 15, kg = lane >> 4;
  const f32x4 zero = {0.f,0.f,0.f,0.f};
  f32x4 acca[2][NT], accb[2][NT];
  #pragma unroll
  for (int s=0;s<2;s++)
    #pragma unroll
    for (int t=0;t<NT;t++){ acca[s][t] = zero; accb[s][t] = zero; }
  #pragma unroll
  for (int c=0;c<4;c++){
    short8 a0 = *(const short8*)(A + (m0 + r)*128 + c*32 + kg*8);
    short8 a1 = *(const short8*)(A + (m0 + 16 + r)*128 + c*32 + kg*8);
    #pragma unroll
    for (int t=0;t<NT;t++){
      short8 ba = *(const short8*)(BTa + (size_t)(t*16 + r)*128 + c*32 + kg*8);
      short8 bb = *(const short8*)(BTb + (size_t)(t*16 + r)*128 + c*32 + kg*8);
      acca[0][t] = __builtin_amdgcn_mfma_f32_16x16x32_bf16(a0, ba, acca[0][t], 0,0,0);
      acca[1][t] = __builtin_amdgcn_mfma_f32_16x16x32_bf16(a1, ba, acca[1][t], 0,0,0);
      accb[0][t] = __builtin_amdgcn_mfma_f32_16x16x32_bf16(a0, bb, accb[0][t], 0,0,0);
      accb[1][t] = __builtin_amdgcn_mfma_f32_16x16x32_bf16(a1, bb, accb[1][t], 0,0,0);
    }
  }
  #pragma unroll
  for (int s=0;s<2;s++)
    #pragma unroll
    for (int t=0;t<NT;t++){
      size_t row = m0 + s*16 + kg*4;
      int col = t*16 + r;
      #pragma unroll
      for (int i=0;i<4;i++){
        Ya[(row+i)*N + col] = f2bf(acca[s][t][i]);
        Yb[(row+i)*N + col] = f2bf(accb[s][t][i]);
      }
    }
}

// ---------- graph-batched GATv2 edge (HC=128, layout B), edge-unroll-4 ----------
// grid (2000,2); block = node, 4 waves x 5 graphs; 4 edges/iter -> 20 independent gathers
__global__ __launch_bounds__(256) void k_edge_g(const bf16* __restrict__ XL, const bf16* __restrict__ XR,
                                                const float2* __restrict__ eaP, const int* __restrict__ off,
                                                const int* __restrict__ csr_src, const float* __restrict__ att,
                                                const float* __restrict__ We, const float* __restrict__ bias,
                                                bf16* __restrict__ Hout){
  int tid = threadIdx.x;
  int ln = tid & 63;                 // channel-pair lane
  int gq = tid >> 6;                 // wave 0..3
  int n  = blockIdx.x;
  int g0 = blockIdx.y*20 + gq*5;     // 5 graphs per wave
  int c0 = 2*ln;
  float av0 = att[c0], av1 = att[c0+1];
  float w00 = We[c0], w01 = We[c0+1];
  float w10 = We[128+c0], w11 = We[128+c0+1];
  const unsigned* XLu = (const unsigned*)XL;
  const unsigned* XRu = (const unsigned*)XR;
  float xr0[5], xr1[5], srun[5], acc0[5], acc1[5];
  #pragma unroll
  for (int t=0;t<5;t++){
    unsigned xu = XRu[((size_t)n*NGRAPH + g0+t)*64 + ln];
    xr0[t] = blo(xu); xr1[t] = bhi(xu);
    srun[t]=0.f; acc0[t]=0.f; acc1[t]=0.f;
  }
  int p0 = off[n], p1 = off[n+1];
  int p = p0;
  for (; p+4 <= p1; p += 4){
    int uA = csr_src[p], uB = csr_src[p+1], uC = csr_src[p+2], uD = csr_src[p+3];
    float2 eA = eaP[p], eB = eaP[p+1], eC = eaP[p+2], eD = eaP[p+3];
    unsigned xlA[5], xlB[5], xlC[5], xlD[5];
    #pragma unroll
    for (int t=0;t<5;t++) xlA[t] = XLu[((size_t)uA*NGRAPH + g0+t)*64 + ln];
    #pragma unroll
    for (int t=0;t<5;t++) xlB[t] = XLu[((size_t)uB*NGRAPH + g0+t)*64 + ln];
    #pragma unroll
    for (int t=0;t<5;t++) xlC[t] = XLu[((size_t)uC*NGRAPH + g0+t)*64 + ln];
    #pragma unroll
    for (int t=0;t<5;t++) xlD[t] = XLu[((size_t)uD*NGRAPH + g0+t)*64 + ln];
    float eA0 = fmaf(eA.x, w00, eA.y*w10), eA1 = fmaf(eA.x, w01, eA.y*w11);
    float eB0 = fmaf(eB.x, w00, eB.y*w10), eB1 = fmaf(eB.x, w01, eB.y*w11);
    float eC0 = fmaf(eC.x, w00, eC.y*w10), eC1 = fmaf(eC.x, w01, eC.y*w11);
    float eD0 = fmaf(eD.x, w00, eD.y*w10), eD1 = fmaf(eD.x, w01, eD.y*w11);
    #pragma unroll
    for (int t=0;t<5;t++){
      float xa0 = blo(xlA[t]), xa1 = bhi(xlA[t]);
      float xb0 = blo(xlB[t]), xb1 = bhi(xlB[t]);
      float xc0 = blo(xlC[t]), xc1 = bhi(xlC[t]);
      float xd0 = blo(xlD[t]), xd1 = bhi(xlD[t]);
      float sa0 = xa0 + xr0[t] + eA0, sa1 = xa1 + xr1[t] + eA1;
      float sb0 = xb0 + xr0[t] + eB0, sb1 = xb1 + xr1[t] + eB1;
      float sc0 = xc0 + xr0[t] + eC0, sc1 = xc1 + xr1[t] + eC1;
      float sd0 = xd0 + xr0[t] + eD0, sd1 = xd1 + xr1[t] + eD1;
      float ma0 = fmaxf(sa0, 0.2f*sa0), ma1 = fmaxf(sa1, 0.2f*sa1);
      float mb0 = fmaxf(sb0, 0.2f*sb0), mb1 = fmaxf(sb1, 0.2f*sb1);
      float mc0 = fmaxf(sc0, 0.2f*sc0), mc1 = fmaxf(sc1, 0.2f*sc1);
      float md0 = fmaxf(sd0, 0.2f*sd0), md1 = fmaxf(sd1, 0.2f*sd1);
      float cA = fmaf(ma0, av0, ma1*av1);
      float cB = fmaf(mb0, av0, mb1*av1);
      float cC = fmaf(mc0, av0, mc1*av1);
      float cD = fmaf(md0, av0, md1*av1);
      #pragma unroll
      for (int d=8; d>=1; d>>=1){
        cA += __shfl_xor(cA, d); cB += __shfl_xor(cB, d);
        cC += __shfl_xor(cC, d); cD += __shfl_xor(cD, d);
      }
      float peA = __expf(cA), peB = __expf(cB), peC = __expf(cC), peD = __expf(cD);
      srun[t] += (peA + peB) + (peC + peD);
      acc0[t] = fmaf(peA, xa0, fmaf(peB, xb0, fmaf(peC, xc0, fmaf(peD, xd0, acc0[t]))));
      acc1[t] = fmaf(peA, xa1, fmaf(peB, xb1, fmaf(peC, xc1, fmaf(peD, xd1, acc1[t]))));
    }
  }
  for (; p < p1; ++p){
    int uA = csr_src[p];
    float2 eA = eaP[p];
    unsigned xlA[5];
    #pragma unroll
    for (int t=0;t<5;t++) xlA[t] = XLu[((size_t)uA*NGRAPH + g0+t)*64 + ln];
    float eA0 = fmaf(eA.x, w00, eA.y*w10);
    float eA1 = fmaf(eA.x, w01, eA.y*w11);
    #pragma unroll
    for (int t=0;t<5;t++){
      float xa0 = blo(xlA[t]), xa1 = bhi(xlA[t]);
      float sa0 = xa0 + xr0[t] + eA0;
      float sa1 = xa1 + xr1[t] + eA1;
      float ma0 = fmaxf(sa0, 0.2f*sa0), ma1 = fmaxf(sa1, 0.2f*sa1);
      float cA = fmaf(ma0, av0, ma1*av1);
      #pragma unroll
      for (int d=8; d>=1; d>>=1) cA += __shfl_xor(cA, d);
      float peA = __expf(cA);
      srun[t] += peA;
      acc0[t] = fmaf(peA, xa0, acc0[t]);
      acc1[t] = fmaf(peA, xa1, acc1[t]);
    }
  }
  #pragma unroll
  for (int t=0;t<5;t++){
    float inv = 1.f/(srun[t] + 1e-16f);
    float o0 = fmaf(acc0[t], inv, bias[c0]);
    float o1 = fmaf(acc1[t], inv, bias[c0+1]);
    o0 = fmaxf(o0, 0.f); o1 = fmaxf(o1, 0.f);
    unsigned r0 = (unsigned)(unsigned short)bfbits(o0);
    unsigned r1 = (unsigned)(unsigned short)bfbits(o1);
    ((unsigned*)Hout)[((size_t)n*NGRAPH + g0+t)*64 + ln] = (r1<<16) | r0;
  }
}

// ---------- GATv2 edge kernel (HC=32 layer, layout B), channel-pair packed, unroll-2 ----------
template<int H, int C>
__global__ __launch_bounds__(256) void k_edge(const bf16* __restrict__ XL, const bf16* __restrict__ XR,
                                              const float2* __restrict__ eaP, const int* __restrict__ off,
                                              const int* __restrict__ csr_src, const float* __restrict__ att,
                                              const float* __restrict__ We, const float* __restrict__ bias,
                                              bf16* __restrict__ Hout){
  const int HC = H*C;
  const int LPN = HC/2;
  const int NPW = 64/LPN;
  const int NPB = 4*NPW;
  int tid = threadIdx.x;
  int lane = tid & 63, wv = tid >> 6;
  int ln = lane % LPN;
  int n  = blockIdx.x*NPB + wv*NPW + lane/LPN;
  int g  = blockIdx.y;
  int c0 = 2*ln;
  const unsigned* XLu = (const unsigned*)XL;
  unsigned xru = ((const unsigned*)XR)[((size_t)n*NGRAPH + g)*LPN + ln];
  float xr0 = blo(xru), xr1 = bhi(xru);
  float av0 = att[c0], av1 = att[c0+1];
  float w00 = We[c0], w01 = We[c0+1];
  float w10 = We[HC+c0], w11 = We[HC+c0+1];
  float srun = 0.f, acc0 = 0.f, acc1 = 0.f;
  int p0 = off[n], p1 = off[n+1];
  int p = p0;
  for (; p+2 <= p1; p += 2){
    int uA = csr_src[p], uB = csr_src[p+1];
    float2 eA = eaP[p], eB = eaP[p+1];
    unsigned xlA = XLu[((size_t)uA*NGRAPH + g)*LPN + ln];
    unsigned xlB = XLu[((size_t)uB*NGRAPH + g)*LPN + ln];
    float xa0 = blo(xlA), xa1 = bhi(xlA);
    float xb0 = blo(xlB), xb1 = bhi(xlB);
    float sa0 = xa0 + fmaf(eA.x,w00, fmaf(eA.y,w10, xr0));
    float sa1 = xa1 + fmaf(eA.x,w01, fmaf(eA.y,w11, xr1));
    float sb0 = xb0 + fmaf(eB.x,w00, fmaf(eB.y,w10, xr0));
    float sb1 = xb1 + fmaf(eB.x,w01, fmaf(eB.y,w11, xr1));
    float ma0 = fmaxf(sa0, 0.2f*sa0), ma1 = fmaxf(sa1, 0.2f*sa1);
    float mb0 = fmaxf(sb0, 0.2f*sb0), mb1 = fmaxf(sb1, 0.2f*sb1);
    float cA = fmaf(ma0,av0, ma1*av1);
    float cB = fmaf(mb0,av0, mb1*av1);
    #pragma unroll
    for (int d=C/4; d>=1; d>>=1){ cA += __shfl_xor(cA, d); cB += __shfl_xor(cB, d); }
    float peA = __expf(cA), peB = __expf(cB);
    srun += peA + peB;
    acc0 = fmaf(peA, xa0, fmaf(peB, xb0, acc0));
    acc1 = fmaf(peA, xa1, fmaf(peB, xb1, acc1));
  }
  if (p < p1){
    int uA = csr_src[p];
    float2 eA = eaP[p];
    unsigned xlA = XLu[((size_t)uA*NGRAPH + g)*LPN + ln];
    float xa0 = blo(xlA), xa1 = bhi(xlA);
    float sa0 = xa0 + fmaf(eA.x,w00, fmaf(eA.y,w10, xr0));
    float sa1 = xa1 + fmaf(eA.x,w01, fmaf(eA.y,w11, xr1));
    float ma0 = fmaxf(sa0, 0.2f*sa0), ma1 = fmaxf(sa1, 0.2f*sa1);
    float cA = fmaf(ma0,av0, ma1*av1);
    #pragma unroll
    for (int d=C/4; d>=1; d>>=1) cA += __shfl_xor(cA, d);
    float peA = __expf(cA);
    srun += peA;
    acc0 = fmaf(peA, xa0, acc0);
    acc1 = fmaf(peA, xa1, acc1);
  }
  float inv = 1.f/(srun + 1e-16f);
  float o0 = fmaf(acc0, inv, bias[c0]);
  float o1 = fmaf(acc1, inv, bias[c0+1]);
  o0 = fmaxf(o0, 0.f); o1 = fmaxf(o1, 0.f);
  unsigned r0 = (unsigned)(unsigned short)bfbits(o0);
  unsigned r1 = (unsigned)(unsigned short)bfbits(o1);
  ((unsigned*)Hout)[((size_t)n*NGRAPH + g)*LPN + ln] = (r1<<16) | r0;
}

// ---------- gates partials: part[ks][bt][j]; emb in layout B [n][g][32] ----------
__global__ __launch_bounds__(256) void k_gates_mf(const bf16* __restrict__ emb, const float* __restrict__ wih,
                                                  float* __restrict__ part){
  const int nk = 2000/GATES_KS;
  int lane = threadIdx.x & 63, wv = threadIdx.x >> 6;
  int r = lane & 15, kg = lane >> 4;
  int j0 = (blockIdx.x*4 + wv)*16;
  int ks = blockIdx.y;
  int k0 = ks*nk*32;
  const f32x4 zero = {0.f,0.f,0.f,0.f};
  f32x4 acc0 = zero, acc1 = zero, acc2 = zero;
  const float* wrow = wih + (size_t)(j0 + r)*64000;
  const bf16* e0p = emb + (size_t)r*32 + kg*8;
  const bf16* e1p = emb + (size_t)(16+r)*32 + kg*8;
  const bf16* e2p = emb + (size_t)(32+r)*32 + kg*8;   // rows 40-47 garbage-safe
  #pragma unroll 2
  for (int s=0; s<nk; ++s){
    int k = k0 + s*32 + kg*8;
    size_t aoff = (size_t)((k0>>5) + s)*(NGRAPH*32);
    float4 wa = *(const float4*)(wrow + k);
    float4 wb = *(const float4*)(wrow + k + 4);
    short8 bfr;
    bfr[0]=bfbits(wa.x); bfr[1]=bfbits(wa.y); bfr[2]=bfbits(wa.z); bfr[3]=bfbits(wa.w);
    bfr[4]=bfbits(wb.x); bfr[5]=bfbits(wb.y); bfr[6]=bfbits(wb.z); bfr[7]=bfbits(wb.w);
    short8 a0 = *(const short8*)(e0p + aoff);
    short8 a1 = *(const short8*)(e1p + aoff);
    short8 a2 = *(const short8*)(e2p + aoff);
    acc0 = __builtin_amdgcn_mfma_f32_16x16x32_bf16(a0, bfr, acc0, 0,0,0);
    acc1 = __builtin_amdgcn_mfma_f32_16x16x32_bf16(a1, bfr, acc1, 0,0,0);
    acc2 = __builtin_amdgcn_mfma_f32_16x16x32_bf16(a2, bfr, acc2, 0,0,0);
  }
  int col = j0 + r;
  float* prow = part + (size_t)ks*40960;
  #pragma unroll
  for (int i=0;i<4;i++){
    int row = kg*4 + i;
    prow[(size_t)row*1024 + col] = acc0[i];
    prow[(size_t)(row+16)*1024 + col] = acc1[i];
    if (row + 32 < 40) prow[(size_t)(row+32)*1024 + col] = acc2[i];
  }
}

// ---------- reduce partials ----------
__global__ __launch_bounds__(256) void k_gred(const float* __restrict__ part, float* __restrict__ gates){
  int idx = blockIdx.x*256 + threadIdx.x;
  float s = 0.f;
  #pragma unroll 8
  for (int ks=0; ks<GATES_KS; ks++) s += part[(size_t)ks*40960 + idx];
  gates[idx] = s;
}

// ---------- fused 10-step LSTM + FC head (R10 version) ----------
__global__ __launch_bounds__(1024) void k_lstm10h(const float* __restrict__ gates, const unsigned* __restrict__ whhT2,
                                                  const float* __restrict__ bih, const float* __restrict__ bhh,
                                                  const float* __restrict__ fc1w, const float* __restrict__ fc1b,
                                                  const float* __restrict__ fc2w, const float* __restrict__ fc2b,
                                                  float* __restrict__ out){
  __shared__ float hs[256];
  __shared__ float g[1024];
  int b = blockIdx.x, j = threadIdx.x;
  float c_reg = 0.f;
  if (j < 256) hs[j] = 0.f;
  float bias = bih[j] + bhh[j];
  __syncthreads();
  for (int t=0;t<10;t++){
    float acc = gates[(size_t)(b*10+t)*1024 + j] + bias;
    #pragma unroll 16
    for (int kp=0;kp<128;kp++){
      unsigned u = whhT2[kp*1024 + j];
      float2 h2 = *(const float2*)&hs[2*kp];
      acc = fmaf(blo(u), h2.x, acc);
      acc = fmaf(bhi(u), h2.y, acc);
    }
    g[j] = acc;
    __syncthreads();
    if (j < 256){
      float i_ = g[j], f_ = g[j+256], gg = g[j+512], o_ = g[j+768];
      float si = 1.f/(1.f+__expf(-i_));
      float sf = 1.f/(1.f+__expf(-f_));
      float so = 1.f/(1.f+__expf(-o_));
      c_reg = sf*c_reg + si*tanhf(gg);
      hs[j] = so*tanhf(c_reg);
    }
    __syncthreads();
  }
  if (j < 512){
    float acc = fc1b[j];
    for (int k=0;k<256;k++){
      float l = fmaxf(hs[k], 0.f);
      acc = fmaf(l, fc1w[k*512 + j], acc);
    }
    float hid = fmaxf(acc, 0.f);
    g[j] = hid * fc2w[j];
  }
  __syncthreads();
  for (int d=256; d>=1; d>>=1){
    if (j < d) g[j] += g[j+d];
    __syncthreads();
  }
  if (j==0) out[b] = g[0] + fc2b[0];
}

extern "C" void kernel_launch(void* const* d_in, const int* in_sizes, int n_in,
                              void* d_out, int out_size, void* d_ws, size_t ws_size,
                              hipStream_t stream){
  const float* x    = (const float*)d_in[0];
  const int*   ei   = (const int*)  d_in[1];
  const float* ea   = (const float*)d_in[2];
  const float* wl0  = (const float*)d_in[3];
  const float* wr0  = (const float*)d_in[4];
  const float* we0  = (const float*)d_in[5];
  const float* att0 = (const float*)d_in[6];
  const float* b0   = (const float*)d_in[7];
  const float* wl1  = (const float*)d_in[8];
  const float* wr1  = (const float*)d_in[9];
  const float* we1  = (const float*)d_in[10];
  const float* att1 = (const float*)d_in[11];
  const float* b1   = (const float*)d_in[12];
  const float* wl2  = (const float*)d_in[13];
  const float* wr2  = (const float*)d_in[14];
  const float* we2  = (const float*)d_in[15];
  const float* att2 = (const float*)d_in[16];
  const float* b2   = (const float*)d_in[17];
  const float* wih  = (const float*)d_in[18];
  const float* whh  = (const float*)d_in[19];
  const float* bih  = (const float*)d_in[20];
  const float* bhh  = (const float*)d_in[21];
  const float* fc1w = (const float*)d_in[22];
  const float* fc1b = (const float*)d_in[23];
  const float* fc2w = (const float*)d_in[24];
  const float* fc2b = (const float*)d_in[25];
  float* out = (float*)d_out;

  char* base = (char*)d_ws; size_t cur = 0;
  auto alloc = [&](size_t bytes)->void*{
    cur = (cur + 255) & ~(size_t)255; void* p = base + cur; cur += bytes; return p;
  };
  float* mean_ea = (float*)alloc(8);
  int*   cnt     = (int*)  alloc((size_t)NNODES*4);
  int*   off     = (int*)  alloc((size_t)(NNODES+1)*4);
  int*   cursor  = (int*)  alloc((size_t)NNODES*4);
  int*   csr_src = (int*)  alloc((size_t)NEDGE*4);
  float2* eaP    = (float2*)alloc((size_t)NEDGE*8);
  bf16*  XL      = (bf16*) alloc((size_t)80000*128*2);
  bf16*  XR      = (bf16*) alloc((size_t)80000*128*2);
  bf16*  HBUF    = (bf16*) alloc((size_t)80000*128*2);
  float* part    = (float*)alloc((size_t)GATES_KS*40960*4);
  float* gates   = (float*)alloc((size_t)40*1024*4);
  unsigned* whhT2= (unsigned*)alloc((size_t)128*1024*4);
  bf16*  bt1a    = (bf16*) alloc((size_t)128*128*2);
  bf16*  bt1b    = (bf16*) alloc((size_t)128*128*2);
  bf16*  bt2a    = (bf16*) alloc((size_t)32*128*2);
  bf16*  bt2b    = (bf16*) alloc((size_t)32*128*2);

  k_setup <<<10689,256,0,stream>>>(ea, mean_ea, whh, whhT2, wl1, wr1, wl2, wr2,
                                   bt1a, bt1b, bt2a, bt2b, cnt, cursor,
                                   x, wl0, wr0, XL, XR);
  k_count   <<<(NEDGE+255)/256,256,0,stream>>>(ei, cnt);
  k_scan    <<<1,64,0,stream>>>(cnt, off);
  k_scatter <<<(NEDGE+255)/256,256,0,stream>>>(ei, off, cursor, ea, mean_ea, csr_src, eaP);

  // Layer 0 edge; all node tensors [n][g][ch] (layout B)
  k_edge_g  <<<dim3(NNODES,2),256,0,stream>>>(XL,XR,eaP,off,csr_src,att0,we0,b0,HBUF);

  // Layer 1
  k_gemm_mf2<128> <<<625,256,0,stream>>>(HBUF, bt1a, bt1b, XL, XR);
  k_edge_g  <<<dim3(NNODES,2),256,0,stream>>>(XL,XR,eaP,off,csr_src,att1,we1,b1,HBUF);

  // Layer 2
  k_gemm_mf2<32> <<<625,256,0,stream>>>(HBUF, bt2a, bt2b, XL, XR);
  k_edge<4,8> <<<dim3(125,40),256,0,stream>>>(XL,XR,eaP,off,csr_src,att2,we2,b2,HBUF);

  // gates
  k_gates_mf<<<dim3(16,GATES_KS),256,0,stream>>>(HBUF, wih, part);
  k_gred    <<<160,256,0,stream>>>(part, gates);

  // LSTM + head (R10 version)
  k_lstm10h<<<4,1024,0,stream>>>(gates, whhT2, bih, bhh, fc1w, fc1b, fc2w, fc2b, out);
}

// Round 16
// 379.276 us; speedup vs baseline: 1.0208x; 1.0208x over previous
//
#include <hip/hip_runtime.h>
#include <hip/hip_bf16.h>
#include <math.h>

typedef __hip_bfloat16 bf16;
typedef __attribute__((ext_vector_type(8))) short short8;
typedef __attribute__((ext_vector_type(4))) float f32x4;

#define NNODES 2000
#define NEDGE_IN 16000
#define NEDGE 18000
#define NGRAPH 40
#define GATES_KS 125

__device__ __forceinline__ float bf2f(bf16 v){ return __bfloat162float(v); }
__device__ __forceinline__ bf16 f2bf(float v){ return __float2bfloat16(v); }
__device__ __forceinline__ short bfbits(float v){ bf16 t = __float2bfloat16(v); return *reinterpret_cast<short*>(&t); }
__device__ __forceinline__ float blo(unsigned u){ return __uint_as_float(u<<16); }
__device__ __forceinline__ float bhi(unsigned u){ return __uint_as_float(u & 0xffff0000u); }

// ---------- fused setup: mean_ea | prep_whh | wcvt | zero | gemm0 (layout-B output) ----------
__global__ __launch_bounds__(256) void k_setup(const float* __restrict__ ea, float* __restrict__ mean_ea,
                        const float* __restrict__ whh, unsigned* __restrict__ whhT2,
                        const float* __restrict__ w1a, const float* __restrict__ w1b,
                        const float* __restrict__ w2a, const float* __restrict__ w2b,
                        bf16* __restrict__ b1a, bf16* __restrict__ b1b,
                        bf16* __restrict__ b2a, bf16* __restrict__ b2b,
                        int* __restrict__ cnt, int* __restrict__ cursor,
                        const float* __restrict__ X, const float* __restrict__ Wa,
                        const float* __restrict__ Wb,
                        bf16* __restrict__ Ya, bf16* __restrict__ Yb){
  __shared__ float smem[2048];
  int bb = blockIdx.x, tid = threadIdx.x;
  if (bb >= 689){
    // ---- layer-0 GEMM (K=8), fused Wl+Wr; output row permuted to [n][g] ----
    int blk = bb - 689;
    for (int i = tid; i < 1024; i += 256){ smem[i] = Wa[i]; smem[1024+i] = Wb[i]; }
    __syncthreads();
    int j  = tid & 127;
    int rg = tid >> 7;
    size_t m0 = (size_t)blk*8 + (size_t)rg*4;      // m = g*2000 + n (4 rows, same g)
    int g = (int)(m0/NNODES), n = (int)(m0%NNODES);
    const float* x0 = X + m0*8;
    float a0=0.f,a1=0.f,a2=0.f,a3=0.f, b0=0.f,b1=0.f,b2=0.f,b3=0.f;
    #pragma unroll
    for (int k=0;k<8;k++){
      float wa = smem[k*128 + j], wb = smem[1024 + k*128 + j];
      float x_0 = x0[k], x_1 = x0[8+k], x_2 = x0[16+k], x_3 = x0[24+k];
      a0 += x_0*wa; a1 += x_1*wa; a2 += x_2*wa; a3 += x_3*wa;
      b0 += x_0*wb; b1 += x_1*wb; b2 += x_2*wb; b3 += x_3*wb;
    }
    const size_t RS = (size_t)NGRAPH*128;
    bf16* ya = Ya + ((size_t)n*NGRAPH + g)*128 + j;
    bf16* yb = Yb + ((size_t)n*NGRAPH + g)*128 + j;
    ya[0]=f2bf(a0); ya[RS]=f2bf(a1); ya[2*RS]=f2bf(a2); ya[3*RS]=f2bf(a3);
    yb[0]=f2bf(b0); yb[RS]=f2bf(b1); yb[2*RS]=f2bf(b2); yb[3*RS]=f2bf(b3);
  } else if (bb == 0){
    float* s0l = smem; float* s1l = smem + 256;
    float s0=0.f, s1=0.f;
    for (int e = tid; e < NEDGE_IN; e += 256){ s0 += ea[2*e]; s1 += ea[2*e+1]; }
    s0l[tid]=s0; s1l[tid]=s1; __syncthreads();
    for (int d=128; d>=1; d>>=1){
      if (tid < d){ s0l[tid]+=s0l[tid+d]; s1l[tid]+=s1l[tid+d]; }
      __syncthreads();
    }
    if (tid==0){ mean_ea[0]=s0l[0]/(float)NEDGE_IN; mean_ea[1]=s1l[0]/(float)NEDGE_IN; }
  } else if (bb < 513){
    int idx = (bb-1)*256 + tid;
    int j = idx >> 7, kp = idx & 127;
    unsigned ulo = (unsigned)(unsigned short)bfbits(whh[j*256 + 2*kp]);
    unsigned uhi = (unsigned)(unsigned short)bfbits(whh[j*256 + 2*kp + 1]);
    whhT2[kp*1024 + j] = (uhi<<16) | ulo;
  } else if (bb < 673){
    int idx = (bb-513)*256 + tid;
    const float* src; bf16* dst; int n, local;
    if (idx < 16384){ src=w1a; dst=b1a; n=128; local=idx; }
    else if (idx < 32768){ src=w1b; dst=b1b; n=128; local=idx-16384; }
    else if (idx < 36864){ src=w2a; dst=b2a; n=32; local=idx-32768; }
    else { src=w2b; dst=b2b; n=32; local=idx-36864; }
    int k = local / n, c = local % n;
    dst[c*128 + k] = f2bf(src[local]);
  } else {
    int idx = (bb-673)*256 + tid;
    if (idx < 2000) cnt[idx] = 0;
    else if (idx < 4000) cursor[idx-2000] = 0;
  }
}

__global__ void k_count(const int* __restrict__ ei, int* __restrict__ cnt){
  int e = blockIdx.x*256 + threadIdx.x;
  if (e >= NEDGE) return;
  int d = (e < NEDGE_IN) ? ei[NEDGE_IN + e] : (e - NEDGE_IN);
  atomicAdd(&cnt[d], 1);
}

__global__ void k_scan(const int* __restrict__ cnt, int* __restrict__ off){
  __shared__ int s[2048];
  int lane = threadIdx.x; // 64 threads
  for (int i = lane; i < 2048; i += 64) s[i] = (i < NNODES) ? cnt[i] : 0;
  __syncthreads();
  int base = lane*32, run = 0;
  for (int j=0;j<32;j++){ int t = s[base+j]; s[base+j] = run; run += t; }
  int x = run;
  for (int d=1; d<64; d<<=1){ int y = __shfl_up(x, d); if (lane >= d) x += y; }
  int chunkOff = x - run;
  for (int j=0;j<32;j++){ int idx = base+j; if (idx <= NNODES) off[idx] = chunkOff + s[idx]; }
}

__global__ void k_scatter(const int* __restrict__ ei, const int* __restrict__ off,
                          int* __restrict__ cursor, const float* __restrict__ ea,
                          const float* __restrict__ mean_ea,
                          int* __restrict__ csr_src, float2* __restrict__ eaP){
  int e = blockIdx.x*256 + threadIdx.x;
  if (e >= NEDGE) return;
  int d, sn; float2 a;
  if (e < NEDGE_IN){ sn = ei[e]; d = ei[NEDGE_IN+e]; a = ((const float2*)ea)[e]; }
  else { sn = e-NEDGE_IN; d = sn; a.x = mean_ea[0]; a.y = mean_ea[1]; }
  int p = off[d] + atomicAdd(&cursor[d], 1);
  csr_src[p] = sn;
  eaP[p] = a;
}

// ---------- MFMA GEMM, fused two B matrices (row-order agnostic) ----------
template<int N>
__global__ __launch_bounds__(256) void k_gemm_mf2(const bf16* __restrict__ A, const bf16* __restrict__ BTa,
                                                  const bf16* __restrict__ BTb,
                                                  bf16* __restrict__ Ya, bf16* __restrict__ Yb){
  const int NT = N/16;
  int lane = threadIdx.x & 63, wv = threadIdx.x >> 6;
  size_t m0 = (size_t)blockIdx.x*128 + (size_t)wv*32;
  int r = lane & 15, kg = lane >> 4;
  const f32x4 zero = {0.f,0.f,0.f,0.f};
  f32x4 acca[2][NT], accb[2][NT];
  #pragma unroll
  for (int s=0;s<2;s++)
    #pragma unroll
    for (int t=0;t<NT;t++){ acca[s][t] = zero; accb[s][t] = zero; }
  #pragma unroll
  for (int c=0;c<4;c++){
    short8 a0 = *(const short8*)(A + (m0 + r)*128 + c*32 + kg*8);
    short8 a1 = *(const short8*)(A + (m0 + 16 + r)*128 + c*32 + kg*8);
    #pragma unroll
    for (int t=0;t<NT;t++){
      short8 ba = *(const short8*)(BTa + (size_t)(t*16 + r)*128 + c*32 + kg*8);
      short8 bb = *(const short8*)(BTb + (size_t)(t*16 + r)*128 + c*32 + kg*8);
      acca[0][t] = __builtin_amdgcn_mfma_f32_16x16x32_bf16(a0, ba, acca[0][t], 0,0,0);
      acca[1][t] = __builtin_amdgcn_mfma_f32_16x16x32_bf16(a1, ba, acca[1][t], 0,0,0);
      accb[0][t] = __builtin_amdgcn_mfma_f32_16x16x32_bf16(a0, bb, accb[0][t], 0,0,0);
      accb[1][t] = __builtin_amdgcn_mfma_f32_16x16x32_bf16(a1, bb, accb[1][t], 0,0,0);
    }
  }
  #pragma unroll
  for (int s=0;s<2;s++)
    #pragma unroll
    for (int t=0;t<NT;t++){
      size_t row = m0 + s*16 + kg*4;
      int col = t*16 + r;
      #pragma unroll
      for (int i=0;i<4;i++){
        Ya[(row+i)*N + col] = f2bf(acca[s][t][i]);
        Yb[(row+i)*N + col] = f2bf(accb[s][t][i]);
      }
    }
}

// ---------- graph-batched GATv2 edge (HC=128, layout B), edge-unroll-2 (R14 version) ----------
__global__ __launch_bounds__(256) void k_edge_g(const bf16* __restrict__ XL, const bf16* __restrict__ XR,
                                                const float2* __restrict__ eaP, const int* __restrict__ off,
                                                const int* __restrict__ csr_src, const float* __restrict__ att,
                                                const float* __restrict__ We, const float* __restrict__ bias,
                                                bf16* __restrict__ Hout){
  int tid = threadIdx.x;
  int ln = tid & 63;                 // channel-pair lane
  int gq = tid >> 6;                 // wave 0..3
  int n  = blockIdx.x;
  int g0 = blockIdx.y*20 + gq*5;     // 5 graphs per wave
  int c0 = 2*ln;
  float av0 = att[c0], av1 = att[c0+1];
  float w00 = We[c0], w01 = We[c0+1];
  float w10 = We[128+c0], w11 = We[128+c0+1];
  const unsigned* XLu = (const unsigned*)XL;
  const unsigned* XRu = (const unsigned*)XR;
  float xr0[5], xr1[5], srun[5], acc0[5], acc1[5];
  #pragma unroll
  for (int t=0;t<5;t++){
    unsigned xu = XRu[((size_t)n*NGRAPH + g0+t)*64 + ln];
    xr0[t] = blo(xu); xr1[t] = bhi(xu);
    srun[t]=0.f; acc0[t]=0.f; acc1[t]=0.f;
  }
  int p0 = off[n], p1 = off[n+1];
  int p = p0;
  for (; p+2 <= p1; p += 2){
    int uA = csr_src[p], uB = csr_src[p+1];
    float2 eA = eaP[p], eB = eaP[p+1];
    unsigned xlA[5], xlB[5];
    #pragma unroll
    for (int t=0;t<5;t++) xlA[t] = XLu[((size_t)uA*NGRAPH + g0+t)*64 + ln];
    #pragma unroll
    for (int t=0;t<5;t++) xlB[t] = XLu[((size_t)uB*NGRAPH + g0+t)*64 + ln];
    float eA0 = fmaf(eA.x, w00, eA.y*w10);
    float eA1 = fmaf(eA.x, w01, eA.y*w11);
    float eB0 = fmaf(eB.x, w00, eB.y*w10);
    float eB1 = fmaf(eB.x, w01, eB.y*w11);
    #pragma unroll
    for (int t=0;t<5;t++){
      float xa0 = blo(xlA[t]), xa1 = bhi(xlA[t]);
      float xb0 = blo(xlB[t]), xb1 = bhi(xlB[t]);
      float sa0 = xa0 + xr0[t] + eA0;
      float sa1 = xa1 + xr1[t] + eA1;
      float sb0 = xb0 + xr0[t] + eB0;
      float sb1 = xb1 + xr1[t] + eB1;
      float ma0 = fmaxf(sa0, 0.2f*sa0), ma1 = fmaxf(sa1, 0.2f*sa1);
      float mb0 = fmaxf(sb0, 0.2f*sb0), mb1 = fmaxf(sb1, 0.2f*sb1);
      float cA = fmaf(ma0, av0, ma1*av1);
      float cB = fmaf(mb0, av0, mb1*av1);
      #pragma unroll
      for (int d=8; d>=1; d>>=1){ cA += __shfl_xor(cA, d); cB += __shfl_xor(cB, d); }
      float peA = __expf(cA), peB = __expf(cB);
      srun[t] += peA + peB;
      acc0[t] = fmaf(peA, xa0, fmaf(peB, xb0, acc0[t]));
      acc1[t] = fmaf(peA, xa1, fmaf(peB, xb1, acc1[t]));
    }
  }
  if (p < p1){
    int uA = csr_src[p];
    float2 eA = eaP[p];
    unsigned xlA[5];
    #pragma unroll
    for (int t=0;t<5;t++) xlA[t] = XLu[((size_t)uA*NGRAPH + g0+t)*64 + ln];
    float eA0 = fmaf(eA.x, w00, eA.y*w10);
    float eA1 = fmaf(eA.x, w01, eA.y*w11);
    #pragma unroll
    for (int t=0;t<5;t++){
      float xa0 = blo(xlA[t]), xa1 = bhi(xlA[t]);
      float sa0 = xa0 + xr0[t] + eA0;
      float sa1 = xa1 + xr1[t] + eA1;
      float ma0 = fmaxf(sa0, 0.2f*sa0), ma1 = fmaxf(sa1, 0.2f*sa1);
      float cA = fmaf(ma0, av0, ma1*av1);
      #pragma unroll
      for (int d=8; d>=1; d>>=1) cA += __shfl_xor(cA, d);
      float peA = __expf(cA);
      srun[t] += peA;
      acc0[t] = fmaf(peA, xa0, acc0[t]);
      acc1[t] = fmaf(peA, xa1, acc1[t]);
    }
  }
  #pragma unroll
  for (int t=0;t<5;t++){
    float inv = 1.f/(srun[t] + 1e-16f);
    float o0 = fmaf(acc0[t], inv, bias[c0]);
    float o1 = fmaf(acc1[t], inv, bias[c0+1]);
    o0 = fmaxf(o0, 0.f); o1 = fmaxf(o1, 0.f);
    unsigned r0 = (unsigned)(unsigned short)bfbits(o0);
    unsigned r1 = (unsigned)(unsigned short)bfbits(o1);
    ((unsigned*)Hout)[((size_t)n*NGRAPH + g0+t)*64 + ln] = (r1<<16) | r0;
  }
}

// ---------- GATv2 edge kernel (HC=32 layer, layout B), channel-pair packed, unroll-2 ----------
template<int H, int C>
__global__ __launch_bounds__(256) void k_edge(const bf16* __restrict__ XL, const bf16* __restrict__ XR,
                                              const float2* __restrict__ eaP, const int* __restrict__ off,
                                              const int* __restrict__ csr_src, const float* __restrict__ att,
                                              const float* __restrict__ We, const float* __restrict__ bias,
                                              bf16* __restrict__ Hout){
  const int HC = H*C;
  const int LPN = HC/2;
  const int NPW = 64/LPN;
  const int NPB = 4*NPW;
  int tid = threadIdx.x;
  int lane = tid & 63, wv = tid >> 6;
  int ln = lane % LPN;
  int n  = blockIdx.x*NPB + wv*NPW + lane/LPN;
  int g  = blockIdx.y;
  int c0 = 2*ln;
  const unsigned* XLu = (const unsigned*)XL;
  unsigned xru = ((const unsigned*)XR)[((size_t)n*NGRAPH + g)*LPN + ln];
  float xr0 = blo(xru), xr1 = bhi(xru);
  float av0 = att[c0], av1 = att[c0+1];
  float w00 = We[c0], w01 = We[c0+1];
  float w10 = We[HC+c0], w11 = We[HC+c0+1];
  float srun = 0.f, acc0 = 0.f, acc1 = 0.f;
  int p0 = off[n], p1 = off[n+1];
  int p = p0;
  for (; p+2 <= p1; p += 2){
    int uA = csr_src[p], uB = csr_src[p+1];
    float2 eA = eaP[p], eB = eaP[p+1];
    unsigned xlA = XLu[((size_t)uA*NGRAPH + g)*LPN + ln];
    unsigned xlB = XLu[((size_t)uB*NGRAPH + g)*LPN + ln];
    float xa0 = blo(xlA), xa1 = bhi(xlA);
    float xb0 = blo(xlB), xb1 = bhi(xlB);
    float sa0 = xa0 + fmaf(eA.x,w00, fmaf(eA.y,w10, xr0));
    float sa1 = xa1 + fmaf(eA.x,w01, fmaf(eA.y,w11, xr1));
    float sb0 = xb0 + fmaf(eB.x,w00, fmaf(eB.y,w10, xr0));
    float sb1 = xb1 + fmaf(eB.x,w01, fmaf(eB.y,w11, xr1));
    float ma0 = fmaxf(sa0, 0.2f*sa0), ma1 = fmaxf(sa1, 0.2f*sa1);
    float mb0 = fmaxf(sb0, 0.2f*sb0), mb1 = fmaxf(sb1, 0.2f*sb1);
    float cA = fmaf(ma0,av0, ma1*av1);
    float cB = fmaf(mb0,av0, mb1*av1);
    #pragma unroll
    for (int d=C/4; d>=1; d>>=1){ cA += __shfl_xor(cA, d); cB += __shfl_xor(cB, d); }
    float peA = __expf(cA), peB = __expf(cB);
    srun += peA + peB;
    acc0 = fmaf(peA, xa0, fmaf(peB, xb0, acc0));
    acc1 = fmaf(peA, xa1, fmaf(peB, xb1, acc1));
  }
  if (p < p1){
    int uA = csr_src[p];
    float2 eA = eaP[p];
    unsigned xlA = XLu[((size_t)uA*NGRAPH + g)*LPN + ln];
    float xa0 = blo(xlA), xa1 = bhi(xlA);
    float sa0 = xa0 + fmaf(eA.x,w00, fmaf(eA.y,w10, xr0));
    float sa1 = xa1 + fmaf(eA.x,w01, fmaf(eA.y,w11, xr1));
    float ma0 = fmaxf(sa0, 0.2f*sa0), ma1 = fmaxf(sa1, 0.2f*sa1);
    float cA = fmaf(ma0,av0, ma1*av1);
    #pragma unroll
    for (int d=C/4; d>=1; d>>=1) cA += __shfl_xor(cA, d);
    float peA = __expf(cA);
    srun += peA;
    acc0 = fmaf(peA, xa0, acc0);
    acc1 = fmaf(peA, xa1, acc1);
  }
  float inv = 1.f/(srun + 1e-16f);
  float o0 = fmaf(acc0, inv, bias[c0]);
  float o1 = fmaf(acc1, inv, bias[c0+1]);
  o0 = fmaxf(o0, 0.f); o1 = fmaxf(o1, 0.f);
  unsigned r0 = (unsigned)(unsigned short)bfbits(o0);
  unsigned r1 = (unsigned)(unsigned short)bfbits(o1);
  ((unsigned*)Hout)[((size_t)n*NGRAPH + g)*LPN + ln] = (r1<<16) | r0;
}

// ---------- gates partials: part[ks][bt][j]; emb in layout B [n][g][32] ----------
__global__ __launch_bounds__(256) void k_gates_mf(const bf16* __restrict__ emb, const float* __restrict__ wih,
                                                  float* __restrict__ part){
  const int nk = 2000/GATES_KS;   // 16 k-steps of 32
  int lane = threadIdx.x & 63, wv = threadIdx.x >> 6;
  int r = lane & 15, kg = lane >> 4;
  int j0 = (blockIdx.x*4 + wv)*16;
  int ks = blockIdx.y;
  int k0 = ks*nk*32;
  const f32x4 zero = {0.f,0.f,0.f,0.f};
  f32x4 acc0 = zero, acc1 = zero, acc2 = zero;
  const float* wrow = wih + (size_t)(j0 + r)*64000;
  const bf16* e0p = emb + (size_t)r*32 + kg*8;
  const bf16* e1p = emb + (size_t)(16+r)*32 + kg*8;
  const bf16* e2p = emb + (size_t)(32+r)*32 + kg*8;   // rows 40-47 garbage-safe
  #pragma unroll 2
  for (int s=0; s<nk; ++s){
    int k = k0 + s*32 + kg*8;
    size_t aoff = (size_t)((k0>>5) + s)*(NGRAPH*32);
    float4 wa = *(const float4*)(wrow + k);
    float4 wb = *(const float4*)(wrow + k + 4);
    short8 bfr;
    bfr[0]=bfbits(wa.x); bfr[1]=bfbits(wa.y); bfr[2]=bfbits(wa.z); bfr[3]=bfbits(wa.w);
    bfr[4]=bfbits(wb.x); bfr[5]=bfbits(wb.y); bfr[6]=bfbits(wb.z); bfr[7]=bfbits(wb.w);
    short8 a0 = *(const short8*)(e0p + aoff);
    short8 a1 = *(const short8*)(e1p + aoff);
    short8 a2 = *(const short8*)(e2p + aoff);
    acc0 = __builtin_amdgcn_mfma_f32_16x16x32_bf16(a0, bfr, acc0, 0,0,0);
    acc1 = __builtin_amdgcn_mfma_f32_16x16x32_bf16(a1, bfr, acc1, 0,0,0);
    acc2 = __builtin_amdgcn_mfma_f32_16x16x32_bf16(a2, bfr, acc2, 0,0,0);
  }
  int col = j0 + r;
  float* prow = part + (size_t)ks*40960;
  #pragma unroll
  for (int i=0;i<4;i++){
    int row = kg*4 + i;
    prow[(size_t)row*1024 + col] = acc0[i];
    prow[(size_t)(row+16)*1024 + col] = acc1[i];
    if (row + 32 < 40) prow[(size_t)(row+32)*1024 + col] = acc2[i];
  }
}

// ---------- reduce partials ----------
__global__ __launch_bounds__(256) void k_gred(const float* __restrict__ part, float* __restrict__ gates){
  int idx = blockIdx.x*256 + threadIdx.x;
  float s = 0.f;
  #pragma unroll 5
  for (int ks=0; ks<GATES_KS; ks++) s += part[(size_t)ks*40960 + idx];
  gates[idx] = s;
}

// ---------- fused 10-step LSTM + FC head (R10 version) ----------
__global__ __launch_bounds__(1024) void k_lstm10h(const float* __restrict__ gates, const unsigned* __restrict__ whhT2,
                                                  const float* __restrict__ bih, const float* __restrict__ bhh,
                                                  const float* __restrict__ fc1w, const float* __restrict__ fc1b,
                                                  const float* __restrict__ fc2w, const float* __restrict__ fc2b,
                                                  float* __restrict__ out){
  __shared__ float hs[256];
  __shared__ float g[1024];
  int b = blockIdx.x, j = threadIdx.x;
  float c_reg = 0.f;
  if (j < 256) hs[j] = 0.f;
  float bias = bih[j] + bhh[j];
  __syncthreads();
  for (int t=0;t<10;t++){
    float acc = gates[(size_t)(b*10+t)*1024 + j] + bias;
    #pragma unroll 16
    for (int kp=0;kp<128;kp++){
      unsigned u = whhT2[kp*1024 + j];
      float2 h2 = *(const float2*)&hs[2*kp];
      acc = fmaf(blo(u), h2.x, acc);
      acc = fmaf(bhi(u), h2.y, acc);
    }
    g[j] = acc;
    __syncthreads();
    if (j < 256){
      float i_ = g[j], f_ = g[j+256], gg = g[j+512], o_ = g[j+768];
      float si = 1.f/(1.f+__expf(-i_));
      float sf = 1.f/(1.f+__expf(-f_));
      float so = 1.f/(1.f+__expf(-o_));
      c_reg = sf*c_reg + si*tanhf(gg);
      hs[j] = so*tanhf(c_reg);
    }
    __syncthreads();
  }
  if (j < 512){
    float acc = fc1b[j];
    for (int k=0;k<256;k++){
      float l = fmaxf(hs[k], 0.f);
      acc = fmaf(l, fc1w[k*512 + j], acc);
    }
    float hid = fmaxf(acc, 0.f);
    g[j] = hid * fc2w[j];
  }
  __syncthreads();
  for (int d=256; d>=1; d>>=1){
    if (j < d) g[j] += g[j+d];
    __syncthreads();
  }
  if (j==0) out[b] = g[0] + fc2b[0];
}

extern "C" void kernel_launch(void* const* d_in, const int* in_sizes, int n_in,
                              void* d_out, int out_size, void* d_ws, size_t ws_size,
                              hipStream_t stream){
  const float* x    = (const float*)d_in[0];
  const int*   ei   = (const int*)  d_in[1];
  const float* ea   = (const float*)d_in[2];
  const float* wl0  = (const float*)d_in[3];
  const float* wr0  = (const float*)d_in[4];
  const float* we0  = (const float*)d_in[5];
  const float* att0 = (const float*)d_in[6];
  const float* b0   = (const float*)d_in[7];
  const float* wl1  = (const float*)d_in[8];
  const float* wr1  = (const float*)d_in[9];
  const float* we1  = (const float*)d_in[10];
  const float* att1 = (const float*)d_in[11];
  const float* b1   = (const float*)d_in[12];
  const float* wl2  = (const float*)d_in[13];
  const float* wr2  = (const float*)d_in[14];
  const float* we2  = (const float*)d_in[15];
  const float* att2 = (const float*)d_in[16];
  const float* b2   = (const float*)d_in[17];
  const float* wih  = (const float*)d_in[18];
  const float* whh  = (const float*)d_in[19];
  const float* bih  = (const float*)d_in[20];
  const float* bhh  = (const float*)d_in[21];
  const float* fc1w = (const float*)d_in[22];
  const float* fc1b = (const float*)d_in[23];
  const float* fc2w = (const float*)d_in[24];
  const float* fc2b = (const float*)d_in[25];
  float* out = (float*)d_out;

  char* base = (char*)d_ws; size_t cur = 0;
  auto alloc = [&](size_t bytes)->void*{
    cur = (cur + 255) & ~(size_t)255; void* p = base + cur; cur += bytes; return p;
  };
  float* mean_ea = (float*)alloc(8);
  int*   cnt     = (int*)  alloc((size_t)NNODES*4);
  int*   off     = (int*)  alloc((size_t)(NNODES+1)*4);
  int*   cursor  = (int*)  alloc((size_t)NNODES*4);
  int*   csr_src = (int*)  alloc((size_t)NEDGE*4);
  float2* eaP    = (float2*)alloc((size_t)NEDGE*8);
  bf16*  XL      = (bf16*) alloc((size_t)80000*128*2);
  bf16*  XR      = (bf16*) alloc((size_t)80000*128*2);
  bf16*  HBUF    = (bf16*) alloc((size_t)80000*128*2);
  float* part    = (float*)alloc((size_t)GATES_KS*40960*4);
  float* gates   = (float*)alloc((size_t)40*1024*4);
  unsigned* whhT2= (unsigned*)alloc((size_t)128*1024*4);
  bf16*  bt1a    = (bf16*) alloc((size_t)128*128*2);
  bf16*  bt1b    = (bf16*) alloc((size_t)128*128*2);
  bf16*  bt2a    = (bf16*) alloc((size_t)32*128*2);
  bf16*  bt2b    = (bf16*) alloc((size_t)32*128*2);

  k_setup <<<10689,256,0,stream>>>(ea, mean_ea, whh, whhT2, wl1, wr1, wl2, wr2,
                                   bt1a, bt1b, bt2a, bt2b, cnt, cursor,
                                   x, wl0, wr0, XL, XR);
  k_count   <<<(NEDGE+255)/256,256,0,stream>>>(ei, cnt);
  k_scan    <<<1,64,0,stream>>>(cnt, off);
  k_scatter <<<(NEDGE+255)/256,256,0,stream>>>(ei, off, cursor, ea, mean_ea, csr_src, eaP);

  // Layer 0 edge; all node tensors [n][g][ch] (layout B)
  k_edge_g  <<<dim3(NNODES,2),256,0,stream>>>(XL,XR,eaP,off,csr_src,att0,we0,b0,HBUF);

  // Layer 1
  k_gemm_mf2<128> <<<625,256,0,stream>>>(HBUF, bt1a, bt1b, XL, XR);
  k_edge_g  <<<dim3(NNODES,2),256,0,stream>>>(XL,XR,eaP,off,csr_src,att1,we1,b1,HBUF);

  // Layer 2
  k_gemm_mf2<32> <<<625,256,0,stream>>>(HBUF, bt2a, bt2b, XL, XR);
  k_edge<4,8> <<<dim3(125,40),256,0,stream>>>(XL,XR,eaP,off,csr_src,att2,we2,b2,HBUF);

  // gates (125 k-splits: 2000 blocks, ~8/CU for w_ih streaming)
  k_gates_mf<<<dim3(16,GATES_KS),256,0,stream>>>(HBUF, wih, part);
  k_gred    <<<160,256,0,stream>>>(part, gates);

  // LSTM + head (R10 version)
  k_lstm10h<<<4,1024,0,stream>>>(gates, whhT2, bih, bhh, fc1w, fc1b, fc2w, fc2b, out);
}

// Round 17
// 350.653 us; speedup vs baseline: 1.1041x; 1.0816x over previous
//
#include <hip/hip_runtime.h>
#include <hip/hip_bf16.h>
#include <math.h>

typedef __hip_bfloat16 bf16;
typedef __attribute__((ext_vector_type(8))) short short8;
typedef __attribute__((ext_vector_type(4))) float f32x4;

#define NNODES 2000
#define NEDGE_IN 16000
#define NEDGE 18000
#define NGRAPH 40
#define GATES_KS 80

__device__ __forceinline__ float bf2f(bf16 v){ return __bfloat162float(v); }
__device__ __forceinline__ bf16 f2bf(float v){ return __float2bfloat16(v); }
__device__ __forceinline__ short bfbits(float v){ bf16 t = __float2bfloat16(v); return *reinterpret_cast<short*>(&t); }
__device__ __forceinline__ float blo(unsigned u){ return __uint_as_float(u<<16); }
__device__ __forceinline__ float bhi(unsigned u){ return __uint_as_float(u & 0xffff0000u); }

// ---------- fused setup: mean_ea | prep_whh | wcvt | zero | gemm0 (layout-B output) ----------
__global__ __launch_bounds__(256) void k_setup(const float* __restrict__ ea, float* __restrict__ mean_ea,
                        const float* __restrict__ whh, unsigned* __restrict__ whhT2,
                        const float* __restrict__ w1a, const float* __restrict__ w1b,
                        const float* __restrict__ w2a, const float* __restrict__ w2b,
                        bf16* __restrict__ b1a, bf16* __restrict__ b1b,
                        bf16* __restrict__ b2a, bf16* __restrict__ b2b,
                        int* __restrict__ cnt, int* __restrict__ cursor,
                        const float* __restrict__ X, const float* __restrict__ Wa,
                        const float* __restrict__ Wb,
                        bf16* __restrict__ Ya, bf16* __restrict__ Yb){
  __shared__ float smem[2048];
  int bb = blockIdx.x, tid = threadIdx.x;
  if (bb >= 689){
    // ---- layer-0 GEMM (K=8), fused Wl+Wr; output row permuted to [n][g] ----
    int blk = bb - 689;
    for (int i = tid; i < 1024; i += 256){ smem[i] = Wa[i]; smem[1024+i] = Wb[i]; }
    __syncthreads();
    int j  = tid & 127;
    int rg = tid >> 7;
    size_t m0 = (size_t)blk*8 + (size_t)rg*4;      // m = g*2000 + n (4 rows, same g)
    int g = (int)(m0/NNODES), n = (int)(m0%NNODES);
    const float* x0 = X + m0*8;
    float a0=0.f,a1=0.f,a2=0.f,a3=0.f, b0=0.f,b1=0.f,b2=0.f,b3=0.f;
    #pragma unroll
    for (int k=0;k<8;k++){
      float wa = smem[k*128 + j], wb = smem[1024 + k*128 + j];
      float x_0 = x0[k], x_1 = x0[8+k], x_2 = x0[16+k], x_3 = x0[24+k];
      a0 += x_0*wa; a1 += x_1*wa; a2 += x_2*wa; a3 += x_3*wa;
      b0 += x_0*wb; b1 += x_1*wb; b2 += x_2*wb; b3 += x_3*wb;
    }
    const size_t RS = (size_t)NGRAPH*128;
    bf16* ya = Ya + ((size_t)n*NGRAPH + g)*128 + j;
    bf16* yb = Yb + ((size_t)n*NGRAPH + g)*128 + j;
    ya[0]=f2bf(a0); ya[RS]=f2bf(a1); ya[2*RS]=f2bf(a2); ya[3*RS]=f2bf(a3);
    yb[0]=f2bf(b0); yb[RS]=f2bf(b1); yb[2*RS]=f2bf(b2); yb[3*RS]=f2bf(b3);
  } else if (bb == 0){
    float* s0l = smem; float* s1l = smem + 256;
    float s0=0.f, s1=0.f;
    for (int e = tid; e < NEDGE_IN; e += 256){ s0 += ea[2*e]; s1 += ea[2*e+1]; }
    s0l[tid]=s0; s1l[tid]=s1; __syncthreads();
    for (int d=128; d>=1; d>>=1){
      if (tid < d){ s0l[tid]+=s0l[tid+d]; s1l[tid]+=s1l[tid+d]; }
      __syncthreads();
    }
    if (tid==0){ mean_ea[0]=s0l[0]/(float)NEDGE_IN; mean_ea[1]=s1l[0]/(float)NEDGE_IN; }
  } else if (bb < 513){
    int idx = (bb-1)*256 + tid;
    int j = idx >> 7, kp = idx & 127;
    unsigned ulo = (unsigned)(unsigned short)bfbits(whh[j*256 + 2*kp]);
    unsigned uhi = (unsigned)(unsigned short)bfbits(whh[j*256 + 2*kp + 1]);
    whhT2[kp*1024 + j] = (uhi<<16) | ulo;
  } else if (bb < 673){
    int idx = (bb-513)*256 + tid;
    const float* src; bf16* dst; int n, local;
    if (idx < 16384){ src=w1a; dst=b1a; n=128; local=idx; }
    else if (idx < 32768){ src=w1b; dst=b1b; n=128; local=idx-16384; }
    else if (idx < 36864){ src=w2a; dst=b2a; n=32; local=idx-32768; }
    else { src=w2b; dst=b2b; n=32; local=idx-36864; }
    int k = local / n, c = local % n;
    dst[c*128 + k] = f2bf(src[local]);
  } else {
    int idx = (bb-673)*256 + tid;
    if (idx < 2000) cnt[idx] = 0;
    else if (idx < 4000) cursor[idx-2000] = 0;
  }
}

__global__ void k_count(const int* __restrict__ ei, int* __restrict__ cnt){
  int e = blockIdx.x*256 + threadIdx.x;
  if (e >= NEDGE) return;
  int d = (e < NEDGE_IN) ? ei[NEDGE_IN + e] : (e - NEDGE_IN);
  atomicAdd(&cnt[d], 1);
}

__global__ void k_scan(const int* __restrict__ cnt, int* __restrict__ off){
  __shared__ int s[2048];
  int lane = threadIdx.x; // 64 threads
  for (int i = lane; i < 2048; i += 64) s[i] = (i < NNODES) ? cnt[i] : 0;
  __syncthreads();
  int base = lane*32, run = 0;
  for (int j=0;j<32;j++){ int t = s[base+j]; s[base+j] = run; run += t; }
  int x = run;
  for (int d=1; d<64; d<<=1){ int y = __shfl_up(x, d); if (lane >= d) x += y; }
  int chunkOff = x - run;
  for (int j=0;j<32;j++){ int idx = base+j; if (idx <= NNODES) off[idx] = chunkOff + s[idx]; }
}

__global__ void k_scatter(const int* __restrict__ ei, const int* __restrict__ off,
                          int* __restrict__ cursor, const float* __restrict__ ea,
                          const float* __restrict__ mean_ea,
                          int* __restrict__ csr_src, float2* __restrict__ eaP){
  int e = blockIdx.x*256 + threadIdx.x;
  if (e >= NEDGE) return;
  int d, sn; float2 a;
  if (e < NEDGE_IN){ sn = ei[e]; d = ei[NEDGE_IN+e]; a = ((const float2*)ea)[e]; }
  else { sn = e-NEDGE_IN; d = sn; a.x = mean_ea[0]; a.y = mean_ea[1]; }
  int p = off[d] + atomicAdd(&cursor[d], 1);
  csr_src[p] = sn;
  eaP[p] = a;
}

// ---------- MFMA GEMM, fused two B matrices (row-order agnostic) ----------
template<int N>
__global__ __launch_bounds__(256) void k_gemm_mf2(const bf16* __restrict__ A, const bf16* __restrict__ BTa,
                                                  const bf16* __restrict__ BTb,
                                                  bf16* __restrict__ Ya, bf16* __restrict__ Yb){
  const int NT = N/16;
  int lane = threadIdx.x & 63, wv = threadIdx.x >> 6;
  size_t m0 = (size_t)blockIdx.x*128 + (size_t)wv*32;
  int r = lane & 15, kg = lane >> 4;
  const f32x4 zero = {0.f,0.f,0.f,0.f};
  f32x4 acca[2][NT], accb[2][NT];
  #pragma unroll
  for (int s=0;s<2;s++)
    #pragma unroll
    for (int t=0;t<NT;t++){ acca[s][t] = zero; accb[s][t] = zero; }
  #pragma unroll
  for (int c=0;c<4;c++){
    short8 a0 = *(const short8*)(A + (m0 + r)*128 + c*32 + kg*8);
    short8 a1 = *(const short8*)(A + (m0 + 16 + r)*128 + c*32 + kg*8);
    #pragma unroll
    for (int t=0;t<NT;t++){
      short8 ba = *(const short8*)(BTa + (size_t)(t*16 + r)*128 + c*32 + kg*8);
      short8 bb = *(const short8*)(BTb + (size_t)(t*16 + r)*128 + c*32 + kg*8);
      acca[0][t] = __builtin_amdgcn_mfma_f32_16x16x32_bf16(a0, ba, acca[0][t], 0,0,0);
      acca[1][t] = __builtin_amdgcn_mfma_f32_16x16x32_bf16(a1, ba, acca[1][t], 0,0,0);
      accb[0][t] = __builtin_amdgcn_mfma_f32_16x16x32_bf16(a0, bb, accb[0][t], 0,0,0);
      accb[1][t] = __builtin_amdgcn_mfma_f32_16x16x32_bf16(a1, bb, accb[1][t], 0,0,0);
    }
  }
  #pragma unroll
  for (int s=0;s<2;s++)
    #pragma unroll
    for (int t=0;t<NT;t++){
      size_t row = m0 + s*16 + kg*4;
      int col = t*16 + r;
      #pragma unroll
      for (int i=0;i<4;i++){
        Ya[(row+i)*N + col] = f2bf(acca[s][t][i]);
        Yb[(row+i)*N + col] = f2bf(accb[s][t][i]);
      }
    }
}

// ---------- graph-batched GATv2 edge (HC=128, layout B), edge-unroll-2 ----------
// grid (2000,2); block = node, 4 waves x 5 graphs; 2 edges/iter -> 10 independent gathers
__global__ __launch_bounds__(256) void k_edge_g(const bf16* __restrict__ XL, const bf16* __restrict__ XR,
                                                const float2* __restrict__ eaP, const int* __restrict__ off,
                                                const int* __restrict__ csr_src, const float* __restrict__ att,
                                                const float* __restrict__ We, const float* __restrict__ bias,
                                                bf16* __restrict__ Hout){
  int tid = threadIdx.x;
  int ln = tid & 63;                 // channel-pair lane
  int gq = tid >> 6;                 // wave 0..3
  int n  = blockIdx.x;
  int g0 = blockIdx.y*20 + gq*5;     // 5 graphs per wave
  int c0 = 2*ln;
  float av0 = att[c0], av1 = att[c0+1];
  float w00 = We[c0], w01 = We[c0+1];
  float w10 = We[128+c0], w11 = We[128+c0+1];
  const unsigned* XLu = (const unsigned*)XL;
  const unsigned* XRu = (const unsigned*)XR;
  float xr0[5], xr1[5], srun[5], acc0[5], acc1[5];
  #pragma unroll
  for (int t=0;t<5;t++){
    unsigned xu = XRu[((size_t)n*NGRAPH + g0+t)*64 + ln];
    xr0[t] = blo(xu); xr1[t] = bhi(xu);
    srun[t]=0.f; acc0[t]=0.f; acc1[t]=0.f;
  }
  int p0 = off[n], p1 = off[n+1];
  int p = p0;
  for (; p+2 <= p1; p += 2){
    int uA = csr_src[p], uB = csr_src[p+1];
    float2 eA = eaP[p], eB = eaP[p+1];
    unsigned xlA[5], xlB[5];
    #pragma unroll
    for (int t=0;t<5;t++) xlA[t] = XLu[((size_t)uA*NGRAPH + g0+t)*64 + ln];
    #pragma unroll
    for (int t=0;t<5;t++) xlB[t] = XLu[((size_t)uB*NGRAPH + g0+t)*64 + ln];
    float eA0 = fmaf(eA.x, w00, eA.y*w10);
    float eA1 = fmaf(eA.x, w01, eA.y*w11);
    float eB0 = fmaf(eB.x, w00, eB.y*w10);
    float eB1 = fmaf(eB.x, w01, eB.y*w11);
    #pragma unroll
    for (int t=0;t<5;t++){
      float xa0 = blo(xlA[t]), xa1 = bhi(xlA[t]);
      float xb0 = blo(xlB[t]), xb1 = bhi(xlB[t]);
      float sa0 = xa0 + xr0[t] + eA0;
      float sa1 = xa1 + xr1[t] + eA1;
      float sb0 = xb0 + xr0[t] + eB0;
      float sb1 = xb1 + xr1[t] + eB1;
      float ma0 = fmaxf(sa0, 0.2f*sa0), ma1 = fmaxf(sa1, 0.2f*sa1);
      float mb0 = fmaxf(sb0, 0.2f*sb0), mb1 = fmaxf(sb1, 0.2f*sb1);
      float cA = fmaf(ma0, av0, ma1*av1);
      float cB = fmaf(mb0, av0, mb1*av1);
      #pragma unroll
      for (int d=8; d>=1; d>>=1){ cA += __shfl_xor(cA, d); cB += __shfl_xor(cB, d); }
      float peA = __expf(cA), peB = __expf(cB);
      srun[t] += peA + peB;
      acc0[t] = fmaf(peA, xa0, fmaf(peB, xb0, acc0[t]));
      acc1[t] = fmaf(peA, xa1, fmaf(peB, xb1, acc1[t]));
    }
  }
  if (p < p1){
    int uA = csr_src[p];
    float2 eA = eaP[p];
    unsigned xlA[5];
    #pragma unroll
    for (int t=0;t<5;t++) xlA[t] = XLu[((size_t)uA*NGRAPH + g0+t)*64 + ln];
    float eA0 = fmaf(eA.x, w00, eA.y*w10);
    float eA1 = fmaf(eA.x, w01, eA.y*w11);
    #pragma unroll
    for (int t=0;t<5;t++){
      float xa0 = blo(xlA[t]), xa1 = bhi(xlA[t]);
      float sa0 = xa0 + xr0[t] + eA0;
      float sa1 = xa1 + xr1[t] + eA1;
      float ma0 = fmaxf(sa0, 0.2f*sa0), ma1 = fmaxf(sa1, 0.2f*sa1);
      float cA = fmaf(ma0, av0, ma1*av1);
      #pragma unroll
      for (int d=8; d>=1; d>>=1) cA += __shfl_xor(cA, d);
      float peA = __expf(cA);
      srun[t] += peA;
      acc0[t] = fmaf(peA, xa0, acc0[t]);
      acc1[t] = fmaf(peA, xa1, acc1[t]);
    }
  }
  #pragma unroll
  for (int t=0;t<5;t++){
    float inv = 1.f/(srun[t] + 1e-16f);
    float o0 = fmaf(acc0[t], inv, bias[c0]);
    float o1 = fmaf(acc1[t], inv, bias[c0+1]);
    o0 = fmaxf(o0, 0.f); o1 = fmaxf(o1, 0.f);
    unsigned r0 = (unsigned)(unsigned short)bfbits(o0);
    unsigned r1 = (unsigned)(unsigned short)bfbits(o1);
    ((unsigned*)Hout)[((size_t)n*NGRAPH + g0+t)*64 + ln] = (r1<<16) | r0;
  }
}

// ---------- GATv2 edge kernel (HC=32 layer, layout B), channel-pair packed, unroll-2 ----------
template<int H, int C>
__global__ __launch_bounds__(256) void k_edge(const bf16* __restrict__ XL, const bf16* __restrict__ XR,
                                              const float2* __restrict__ eaP, const int* __restrict__ off,
                                              const int* __restrict__ csr_src, const float* __restrict__ att,
                                              const float* __restrict__ We, const float* __restrict__ bias,
                                              bf16* __restrict__ Hout){
  const int HC = H*C;
  const int LPN = HC/2;
  const int NPW = 64/LPN;
  const int NPB = 4*NPW;
  int tid = threadIdx.x;
  int lane = tid & 63, wv = tid >> 6;
  int ln = lane % LPN;
  int n  = blockIdx.x*NPB + wv*NPW + lane/LPN;
  int g  = blockIdx.y;
  int c0 = 2*ln;
  const unsigned* XLu = (const unsigned*)XL;
  unsigned xru = ((const unsigned*)XR)[((size_t)n*NGRAPH + g)*LPN + ln];
  float xr0 = blo(xru), xr1 = bhi(xru);
  float av0 = att[c0], av1 = att[c0+1];
  float w00 = We[c0], w01 = We[c0+1];
  float w10 = We[HC+c0], w11 = We[HC+c0+1];
  float srun = 0.f, acc0 = 0.f, acc1 = 0.f;
  int p0 = off[n], p1 = off[n+1];
  int p = p0;
  for (; p+2 <= p1; p += 2){
    int uA = csr_src[p], uB = csr_src[p+1];
    float2 eA = eaP[p], eB = eaP[p+1];
    unsigned xlA = XLu[((size_t)uA*NGRAPH + g)*LPN + ln];
    unsigned xlB = XLu[((size_t)uB*NGRAPH + g)*LPN + ln];
    float xa0 = blo(xlA), xa1 = bhi(xlA);
    float xb0 = blo(xlB), xb1 = bhi(xlB);
    float sa0 = xa0 + fmaf(eA.x,w00, fmaf(eA.y,w10, xr0));
    float sa1 = xa1 + fmaf(eA.x,w01, fmaf(eA.y,w11, xr1));
    float sb0 = xb0 + fmaf(eB.x,w00, fmaf(eB.y,w10, xr0));
    float sb1 = xb1 + fmaf(eB.x,w01, fmaf(eB.y,w11, xr1));
    float ma0 = fmaxf(sa0, 0.2f*sa0), ma1 = fmaxf(sa1, 0.2f*sa1);
    float mb0 = fmaxf(sb0, 0.2f*sb0), mb1 = fmaxf(sb1, 0.2f*sb1);
    float cA = fmaf(ma0,av0, ma1*av1);
    float cB = fmaf(mb0,av0, mb1*av1);
    #pragma unroll
    for (int d=C/4; d>=1; d>>=1){ cA += __shfl_xor(cA, d); cB += __shfl_xor(cB, d); }
    float peA = __expf(cA), peB = __expf(cB);
    srun += peA + peB;
    acc0 = fmaf(peA, xa0, fmaf(peB, xb0, acc0));
    acc1 = fmaf(peA, xa1, fmaf(peB, xb1, acc1));
  }
  if (p < p1){
    int uA = csr_src[p];
    float2 eA = eaP[p];
    unsigned xlA = XLu[((size_t)uA*NGRAPH + g)*LPN + ln];
    float xa0 = blo(xlA), xa1 = bhi(xlA);
    float sa0 = xa0 + fmaf(eA.x,w00, fmaf(eA.y,w10, xr0));
    float sa1 = xa1 + fmaf(eA.x,w01, fmaf(eA.y,w11, xr1));
    float ma0 = fmaxf(sa0, 0.2f*sa0), ma1 = fmaxf(sa1, 0.2f*sa1);
    float cA = fmaf(ma0,av0, ma1*av1);
    #pragma unroll
    for (int d=C/4; d>=1; d>>=1) cA += __shfl_xor(cA, d);
    float peA = __expf(cA);
    srun += peA;
    acc0 = fmaf(peA, xa0, acc0);
    acc1 = fmaf(peA, xa1, acc1);
  }
  float inv = 1.f/(srun + 1e-16f);
  float o0 = fmaf(acc0, inv, bias[c0]);
  float o1 = fmaf(acc1, inv, bias[c0+1]);
  o0 = fmaxf(o0, 0.f); o1 = fmaxf(o1, 0.f);
  unsigned r0 = (unsigned)(unsigned short)bfbits(o0);
  unsigned r1 = (unsigned)(unsigned short)bfbits(o1);
  ((unsigned*)Hout)[((size_t)n*NGRAPH + g)*LPN + ln] = (r1<<16) | r0;
}

// ---------- gates partials: part[ks][bt][j]; emb in layout B [n][g][32] ----------
__global__ __launch_bounds__(256) void k_gates_mf(const bf16* __restrict__ emb, const float* __restrict__ wih,
                                                  float* __restrict__ part){
  const int nk = 2000/GATES_KS;
  int lane = threadIdx.x & 63, wv = threadIdx.x >> 6;
  int r = lane & 15, kg = lane >> 4;
  int j0 = (blockIdx.x*4 + wv)*16;
  int ks = blockIdx.y;
  int k0 = ks*nk*32;
  const f32x4 zero = {0.f,0.f,0.f,0.f};
  f32x4 acc0 = zero, acc1 = zero, acc2 = zero;
  const float* wrow = wih + (size_t)(j0 + r)*64000;
  const bf16* e0p = emb + (size_t)r*32 + kg*8;
  const bf16* e1p = emb + (size_t)(16+r)*32 + kg*8;
  const bf16* e2p = emb + (size_t)(32+r)*32 + kg*8;   // rows 40-47 garbage-safe
  #pragma unroll 2
  for (int s=0; s<nk; ++s){
    int k = k0 + s*32 + kg*8;
    size_t aoff = (size_t)((k0>>5) + s)*(NGRAPH*32);
    float4 wa = *(const float4*)(wrow + k);
    float4 wb = *(const float4*)(wrow + k + 4);
    short8 bfr;
    bfr[0]=bfbits(wa.x); bfr[1]=bfbits(wa.y); bfr[2]=bfbits(wa.z); bfr[3]=bfbits(wa.w);
    bfr[4]=bfbits(wb.x); bfr[5]=bfbits(wb.y); bfr[6]=bfbits(wb.z); bfr[7]=bfbits(wb.w);
    short8 a0 = *(const short8*)(e0p + aoff);
    short8 a1 = *(const short8*)(e1p + aoff);
    short8 a2 = *(const short8*)(e2p + aoff);
    acc0 = __builtin_amdgcn_mfma_f32_16x16x32_bf16(a0, bfr, acc0, 0,0,0);
    acc1 = __builtin_amdgcn_mfma_f32_16x16x32_bf16(a1, bfr, acc1, 0,0,0);
    acc2 = __builtin_amdgcn_mfma_f32_16x16x32_bf16(a2, bfr, acc2, 0,0,0);
  }
  int col = j0 + r;
  float* prow = part + (size_t)ks*40960;
  #pragma unroll
  for (int i=0;i<4;i++){
    int row = kg*4 + i;
    prow[(size_t)row*1024 + col] = acc0[i];
    prow[(size_t)(row+16)*1024 + col] = acc1[i];
    if (row + 32 < 40) prow[(size_t)(row+32)*1024 + col] = acc2[i];
  }
}

// ---------- reduce partials ----------
__global__ __launch_bounds__(256) void k_gred(const float* __restrict__ part, float* __restrict__ gates){
  int idx = blockIdx.x*256 + threadIdx.x;
  float s = 0.f;
  #pragma unroll 8
  for (int ks=0; ks<GATES_KS; ks++) s += part[(size_t)ks*40960 + idx];
  gates[idx] = s;
}

// ---------- fused 10-step LSTM + FC head ----------
__global__ __launch_bounds__(1024) void k_lstm10h(const float* __restrict__ gates, const unsigned* __restrict__ whhT2,
                                                  const float* __restrict__ bih, const float* __restrict__ bhh,
                                                  const float* __restrict__ fc1w, const float* __restrict__ fc1b,
                                                  const float* __restrict__ fc2w, const float* __restrict__ fc2b,
                                                  float* __restrict__ out){
  __shared__ float hs[256];
  __shared__ float g[1024];
  int b = blockIdx.x, j = threadIdx.x;
  float c_reg = 0.f;
  if (j < 256) hs[j] = 0.f;
  float bias = bih[j] + bhh[j];
  __syncthreads();
  for (int t=0;t<10;t++){
    float acc = gates[(size_t)(b*10+t)*1024 + j] + bias;
    #pragma unroll 16
    for (int kp=0;kp<128;kp++){
      unsigned u = whhT2[kp*1024 + j];
      float2 h2 = *(const float2*)&hs[2*kp];
      acc = fmaf(blo(u), h2.x, acc);
      acc = fmaf(bhi(u), h2.y, acc);
    }
    g[j] = acc;
    __syncthreads();
    if (j < 256){
      float i_ = g[j], f_ = g[j+256], gg = g[j+512], o_ = g[j+768];
      float si = 1.f/(1.f+__expf(-i_));
      float sf = 1.f/(1.f+__expf(-f_));
      float so = 1.f/(1.f+__expf(-o_));
      c_reg = sf*c_reg + si*tanhf(gg);
      hs[j] = so*tanhf(c_reg);
    }
    __syncthreads();
  }
  if (j < 512){
    float acc = fc1b[j];
    for (int k=0;k<256;k++){
      float l = fmaxf(hs[k], 0.f);
      acc = fmaf(l, fc1w[k*512 + j], acc);
    }
    float hid = fmaxf(acc, 0.f);
    g[j] = hid * fc2w[j];
  }
  __syncthreads();
  for (int d=256; d>=1; d>>=1){
    if (j < d) g[j] += g[j+d];
    __syncthreads();
  }
  if (j==0) out[b] = g[0] + fc2b[0];
}

extern "C" void kernel_launch(void* const* d_in, const int* in_sizes, int n_in,
                              void* d_out, int out_size, void* d_ws, size_t ws_size,
                              hipStream_t stream){
  const float* x    = (const float*)d_in[0];
  const int*   ei   = (const int*)  d_in[1];
  const float* ea   = (const float*)d_in[2];
  const float* wl0  = (const float*)d_in[3];
  const float* wr0  = (const float*)d_in[4];
  const float* we0  = (const float*)d_in[5];
  const float* att0 = (const float*)d_in[6];
  const float* b0   = (const float*)d_in[7];
  const float* wl1  = (const float*)d_in[8];
  const float* wr1  = (const float*)d_in[9];
  const float* we1  = (const float*)d_in[10];
  const float* att1 = (const float*)d_in[11];
  const float* b1   = (const float*)d_in[12];
  const float* wl2  = (const float*)d_in[13];
  const float* wr2  = (const float*)d_in[14];
  const float* we2  = (const float*)d_in[15];
  const float* att2 = (const float*)d_in[16];
  const float* b2   = (const float*)d_in[17];
  const float* wih  = (const float*)d_in[18];
  const float* whh  = (const float*)d_in[19];
  const float* bih  = (const float*)d_in[20];
  const float* bhh  = (const float*)d_in[21];
  const float* fc1w = (const float*)d_in[22];
  const float* fc1b = (const float*)d_in[23];
  const float* fc2w = (const float*)d_in[24];
  const float* fc2b = (const float*)d_in[25];
  float* out = (float*)d_out;

  char* base = (char*)d_ws; size_t cur = 0;
  auto alloc = [&](size_t bytes)->void*{
    cur = (cur + 255) & ~(size_t)255; void* p = base + cur; cur += bytes; return p;
  };
  float* mean_ea = (float*)alloc(8);
  int*   cnt     = (int*)  alloc((size_t)NNODES*4);
  int*   off     = (int*)  alloc((size_t)(NNODES+1)*4);
  int*   cursor  = (int*)  alloc((size_t)NNODES*4);
  int*   csr_src = (int*)  alloc((size_t)NEDGE*4);
  float2* eaP    = (float2*)alloc((size_t)NEDGE*8);
  bf16*  XL      = (bf16*) alloc((size_t)80000*128*2);
  bf16*  XR      = (bf16*) alloc((size_t)80000*128*2);
  bf16*  HBUF    = (bf16*) alloc((size_t)80000*128*2);
  float* part    = (float*)alloc((size_t)GATES_KS*40960*4);
  float* gates   = (float*)alloc((size_t)40*1024*4);
  unsigned* whhT2= (unsigned*)alloc((size_t)128*1024*4);
  bf16*  bt1a    = (bf16*) alloc((size_t)128*128*2);
  bf16*  bt1b    = (bf16*) alloc((size_t)128*128*2);
  bf16*  bt2a    = (bf16*) alloc((size_t)32*128*2);
  bf16*  bt2b    = (bf16*) alloc((size_t)32*128*2);

  k_setup <<<10689,256,0,stream>>>(ea, mean_ea, whh, whhT2, wl1, wr1, wl2, wr2,
                                   bt1a, bt1b, bt2a, bt2b, cnt, cursor,
                                   x, wl0, wr0, XL, XR);
  k_count   <<<(NEDGE+255)/256,256,0,stream>>>(ei, cnt);
  k_scan    <<<1,64,0,stream>>>(cnt, off);
  k_scatter <<<(NEDGE+255)/256,256,0,stream>>>(ei, off, cursor, ea, mean_ea, csr_src, eaP);

  // Layer 0 edge; all node tensors [n][g][ch] (layout B)
  k_edge_g  <<<dim3(NNODES,2),256,0,stream>>>(XL,XR,eaP,off,csr_src,att0,we0,b0,HBUF);

  // Layer 1
  k_gemm_mf2<128> <<<625,256,0,stream>>>(HBUF, bt1a, bt1b, XL, XR);
  k_edge_g  <<<dim3(NNODES,2),256,0,stream>>>(XL,XR,eaP,off,csr_src,att1,we1,b1,HBUF);

  // Layer 2
  k_gemm_mf2<32> <<<625,256,0,stream>>>(HBUF, bt2a, bt2b, XL, XR);
  k_edge<4,8> <<<dim3(125,40),256,0,stream>>>(XL,XR,eaP,off,csr_src,att2,we2,b2,HBUF);

  // gates
  k_gates_mf<<<dim3(16,GATES_KS),256,0,stream>>>(HBUF, wih, part);
  k_gred    <<<160,256,0,stream>>>(part, gates);

  // LSTM + head
  k_lstm10h<<<4,1024,0,stream>>>(gates, whhT2, bih, bhh, fc1w, fc1b, fc2w, fc2b, out);
}